// Round 17
// baseline (312.503 us; speedup 1.0000x reference)
//
#include <hip/hip_runtime.h>

typedef unsigned short u16;
typedef __attribute__((ext_vector_type(8))) short bf16x8;
typedef __attribute__((ext_vector_type(4))) float f32x4;

__device__ __forceinline__ u16 f2bf(float f) {
  union { float f; unsigned u; } v; v.f = f;
  unsigned r = v.u + 0x7FFFu + ((v.u >> 16) & 1u);
  return (u16)(r >> 16);
}
__device__ __forceinline__ float bf2f(u16 h) {
  union { unsigned u; float f; } v; v.u = ((unsigned)h) << 16; return v.f;
}
__device__ __forceinline__ unsigned pk2(float a, float b) {
  return (unsigned)f2bf(a) | ((unsigned)f2bf(b) << 16);
}
__device__ __forceinline__ unsigned cvtpk(float a, float b) {
  unsigned r;
  asm("v_cvt_pk_bf16_f32 %0, %1, %2" : "=v"(r) : "v"(a), "v"(b));
  return r;
}
__device__ __forceinline__ void gld16(const void* g, void* l) {
  __builtin_amdgcn_global_load_lds(
      (const __attribute__((address_space(1))) unsigned int*)g,
      (__attribute__((address_space(3))) unsigned int*)l, 16, 0, 0);
}
template <int N>
__device__ __forceinline__ void waitvm() {
  asm volatile("s_waitcnt vmcnt(%0)" ::"n"(N) : "memory");
}
__device__ __forceinline__ void waitlgkm0() {
  asm volatile("s_waitcnt lgkmcnt(0)" ::: "memory");
}

// All weight transposes in one kernel. in [256][C] f32 -> out [Cout][256] bf16.
__global__ __launch_bounds__(256)
void prep_w_k(const float* __restrict__ Wp, const float* __restrict__ Wg,
              const float* __restrict__ Wb, const float* __restrict__ W1,
              const float* __restrict__ W2, u16* __restrict__ WpT,
              u16* __restrict__ WgbT, u16* __restrict__ W1T,
              u16* __restrict__ W2T) {
  int z = blockIdx.z;
  const float* in; u16* out; int C = 256;
  if (z == 0) { in = Wp; out = WpT; }
  else if (z == 1) { in = Wg; out = WgbT; }
  else if (z == 2) { in = Wb; out = WgbT + 65536; }
  else if (z == 3) { in = W1; out = W1T; }
  else { in = W2; out = W2T; C = 40; if (blockIdx.x >= 2) return; }
  __shared__ float tile[32][33];
  int tj = blockIdx.x * 32, ti = blockIdx.y * 32;
  int t = threadIdx.x, c = t & 31, r0 = t >> 5;
#pragma unroll
  for (int p = 0; p < 4; ++p) {
    int r = r0 + p * 8;
    tile[r][c] = (tj + c < C) ? in[(size_t)(ti + r) * C + (tj + c)] : 0.f;
  }
  __syncthreads();
#pragma unroll
  for (int p = 0; p < 4; ++p) {
    int rr = r0 + p * 8;
    out[(size_t)(tj + rr) * 256 + (ti + c)] = f2bf(tile[c][rr]);
  }
}

// x [8192][256] f32 -> xT [256][8192] bf16 and xbf [8192][256] bf16.
// Blocks with tj==0 also extract dd[row] = bf16-rounded adj_a[row][row].
__global__ __launch_bounds__(256)
void prep_x_k(const float* __restrict__ x, const float* __restrict__ adj,
              u16* __restrict__ xT, u16* __restrict__ xbf,
              float* __restrict__ dd) {
  __shared__ float tile[32][33];
  int tj = blockIdx.x * 32, ti = blockIdx.y * 32;
  int t = threadIdx.x, c = t & 31, r0 = t >> 5;
#pragma unroll
  for (int p = 0; p < 4; ++p) {
    int r = r0 + p * 8;
    float v = x[(size_t)(ti + r) * 256 + (tj + c)];
    tile[r][c] = v;
    xbf[(size_t)(ti + r) * 256 + (tj + c)] = f2bf(v);
  }
  if (tj == 0 && t < 32) {
    int r = ti + t;
    dd[r] = bf2f(f2bf(adj[(size_t)r * 8193]));
  }
  __syncthreads();
#pragma unroll
  for (int p = 0; p < 4; ++p) {
    int rr = r0 + p * 8;
    xT[(size_t)(tj + rr) * 8192 + (ti + c)] = f2bf(tile[c][rr]);
  }
}

// ============ pipelined fp32-A GEMM body (2-deep, counted vmcnt) ============
// BM=64, BK=64, KP=2048 (NSTEP=32), 8 waves (2Mx4N). A fp32 reg-staged->bf16
// LDS (2x8KB); B bf16 gld16 (2x BN*128B). 2 barriers/iter; vmcnt never 0
// mid-loop. STORE: write bf16 A copy. PACK: bf16-packed partials (BN=256).
template <int BN, bool STORE, bool PACK>
__device__ __forceinline__ void fp32_pipe(
    const float* __restrict__ Av, const u16* __restrict__ Bt,
    void* __restrict__ part, u16* __restrict__ Aout,
    u16* sA, u16* sB, int mBase, int kpBase, int kp, int ph) {
  constexpr int BK = 64;
  constexpr int NSTEP = 2048 / BK;  // 32
  constexpr int NB = BN / 64;       // B gld16 issues/thread
  constexpr int S = STORE ? 1 : 0;
  constexpr int FR = 2;
  constexpr int FC = BN / 64;
  const int t = threadIdx.x, lane = t & 63, w = t >> 6;
  const int l15 = lane & 15, lhi = lane >> 4;
  const int waveM = (w >> 2) * 32;
  const int waveN = (w & 3) * (BN / 4);
  const int rA = t >> 3, qA = t & 7;
  const int swA = (rA & 7) << 4;

  f32x4 acc[FR][FC];
#pragma unroll
  for (int a = 0; a < FR; ++a)
#pragma unroll
    for (int b = 0; b < FC; ++b) acc[a][b] = (f32x4){0.f, 0.f, 0.f, 0.f};

  float4 a0, a1;
  auto k0of = [&](int tt) { return kpBase + ((tt + ph) & (NSTEP - 1)) * BK; };
  auto issueB = [&](int tt, int buf) {
    const int k0 = k0of(tt);
#pragma unroll
    for (int i = 0; i < NB; ++i) {
      int L = i * 8192 + t * 16;
      int n = L >> 7;
      int kb = (L & 127) ^ ((n & 7) << 4);
      gld16((const char*)Bt + ((size_t)n << 14) + ((size_t)k0 << 1) + kb,
            (char*)(sB + buf * (BN * 64)) + L);
    }
  };
  auto issueA = [&](int tt) {
    const float* gp = Av + ((size_t)(mBase + rA) << 13) + k0of(tt) + qA * 8;
    a0 = *(const float4*)gp;
    a1 = *(const float4*)(gp + 4);
  };
  auto writeA = [&](int tt, int buf) {
    uint4 q;
    q.x = cvtpk(a0.x, a0.y); q.y = cvtpk(a0.z, a0.w);
    q.z = cvtpk(a1.x, a1.y); q.w = cvtpk(a1.z, a1.w);
    *(uint4*)((char*)(sA + buf * 4096) + rA * 128 + ((qA * 16) ^ swA)) = q;
    if (STORE) {
      u16* dst = Aout + ((size_t)(mBase + rA) << 13) + k0of(tt) + qA * 8;
      *(uint4*)dst = q;
    }
  };

  // prologue
  issueA(0);
  issueB(0, 0);
  waitvm<NB>();      // A(0) regs ready (NB newer B(0) ops outstanding)
  writeA(0, 0);      // + store(0) if STORE
  issueA(1);
  waitlgkm0();

  for (int tt = 0; tt < NSTEP; ++tt) {
    const int buf = tt & 1;
    if (tt + 1 < NSTEP) {
      issueB(tt + 1, buf ^ 1);
      waitvm<NB + 2 + S>();  // drain B(tt); newer: store(tt)S + A(tt+1)2 + B(tt+1)NB
    } else {
      waitvm<S>();           // drain B(tt); only store(tt) newer
    }
    __builtin_amdgcn_s_barrier();
    // ---- compute tile tt ----
    const u16* pa = sA + buf * 4096;
    const u16* pb = sB + buf * (BN * 64);
#pragma unroll
    for (int ks = 0; ks < 2; ++ks) {
      bf16x8 av[FR], bv[FC];
#pragma unroll
      for (int fr = 0; fr < FR; ++fr) {
        int row = waveM + fr * 16 + l15;
        int off = row * 128 + ((ks * 64 + lhi * 16) ^ ((row & 7) << 4));
        av[fr] = *(const bf16x8*)((const char*)pa + off);
      }
#pragma unroll
      for (int fc = 0; fc < FC; ++fc) {
        int n = waveN + fc * 16 + l15;
        int off = n * 128 + ((ks * 64 + lhi * 16) ^ ((n & 7) << 4));
        bv[fc] = *(const bf16x8*)((const char*)pb + off);
      }
#pragma unroll
      for (int fr = 0; fr < FR; ++fr)
#pragma unroll
        for (int fc = 0; fc < FC; ++fc)
          acc[fr][fc] = __builtin_amdgcn_mfma_f32_16x16x32_bf16(
              av[fr], bv[fc], acc[fr][fc], 0, 0, 0);
    }
    // ---- finish staging tile tt+1 ----
    if (tt + 1 < NSTEP) {
      waitvm<NB>();          // A(tt+1) regs ready (B(tt+1) NB newer)
      writeA(tt + 1, buf ^ 1);
      if (tt + 2 < NSTEP) issueA(tt + 2);
      waitlgkm0();
    }
    __builtin_amdgcn_s_barrier();
  }

  if (PACK) {
    unsigned* pp = (unsigned*)part + (size_t)kp * 8192 * 128 + (size_t)mBase * 128;
#pragma unroll
    for (int fr = 0; fr < FR; ++fr)
#pragma unroll
      for (int fcp = 0; fcp < FC / 2; ++fcp) {
        int g = (waveN >> 5) + fcp;
        int r0 = waveM + fr * 16 + lhi * 4;
#pragma unroll
        for (int j = 0; j < 4; ++j)
          pp[(size_t)(r0 + j) * 128 + g * 16 + l15] =
              cvtpk(acc[fr][2 * fcp][j], acc[fr][2 * fcp + 1][j]);
      }
  } else {
    float* pf = (float*)part + (size_t)kp * 8192 * BN + (size_t)mBase * BN;
#pragma unroll
    for (int fr = 0; fr < FR; ++fr)
#pragma unroll
      for (int fc = 0; fc < FC; ++fc) {
        int col = waveN + fc * 16 + l15;
        int r0 = waveM + fr * 16 + lhi * 4;
#pragma unroll
        for (int j = 0; j < 4; ++j)
          pf[(size_t)(r0 + j) * BN + col] = acc[fr][fc][j];
      }
  }
}

// Dual fp32 big GEMM: grid 1024, blocks 0-511 adj_f->part1, 512-1023
// adj_a->part2 (+bf16 writeback). Anti-phase via (blockIdx>>8)&1.
template <bool WRB2>
__global__ __launch_bounds__(512, 4)
void bgemm2_k(const float* __restrict__ A1, const u16* __restrict__ Bt1,
              unsigned* __restrict__ part1, const float* __restrict__ A2,
              const u16* __restrict__ Bt2, unsigned* __restrict__ part2,
              u16* __restrict__ Aout) {
  __shared__ u16 sA[2 * 4096];
  __shared__ u16 sB[2 * 256 * 64];
  const bool second = blockIdx.x >= 512;
  const int bx = blockIdx.x & 511;
  const int ph = ((blockIdx.x >> 8) & 1) * 16;
  const int xcd = bx & 7, idx = bx >> 3;
  const int kp = xcd >> 1;
  const int m = (idx << 1) | (xcd & 1);
  const int mBase = m * 64;
  const int kpBase = kp * 2048;
  if (second) {
    if (WRB2)
      fp32_pipe<256, true, true>(A2, Bt2, part2, Aout, sA, sB, mBase, kpBase, kp, ph);
    else
      fp32_pipe<256, false, true>(A2, Bt2, part2, nullptr, sA, sB, mBase, kpBase, kp, ph);
  } else {
    fp32_pipe<256, false, true>(A1, Bt1, part1, nullptr, sA, sB, mBase, kpBase, kp, ph);
  }
}

// fp32 fallback single GEMM (no adj_bf workspace case).
template <int BN, bool PACK>
__global__ __launch_bounds__(512, 4)
void bgemm_f32_k(const float* __restrict__ Av, const u16* __restrict__ Bt,
                 void* __restrict__ part) {
  __shared__ u16 sA[2 * 4096];
  __shared__ u16 sB[2 * BN * 64];
  const int bx = blockIdx.x & 511;
  const int ph = ((blockIdx.x >> 8) & 1) * 16;
  const int xcd = bx & 7, idx = bx >> 3;
  const int kp = xcd >> 1;
  const int m = (idx << 1) | (xcd & 1);
  fp32_pipe<BN, false, PACK>(Av, Bt, part, nullptr, sA, sB, m * 64, kp * 2048, kp, ph);
}

// Pipelined bf16-A GEMM (gld16 for A and B, counted vmcnt, 2-deep).
template <int BN, bool PACK>
__global__ __launch_bounds__(512, 4)
void bgemm_abf_k(const u16* __restrict__ Av, const u16* __restrict__ Bt,
                 void* __restrict__ part) {
  constexpr int BK = 64;
  constexpr int NSTEP = 2048 / BK;  // 32
  constexpr int NB = BN / 64;
  constexpr int NI = 1 + NB;        // A(1) + B(NB) gld16 per tile
  constexpr int FR = 2;
  constexpr int FC = BN / 64;
  __shared__ u16 sA[2 * 4096];
  __shared__ u16 sB[2 * BN * 64];
  const int t = threadIdx.x, lane = t & 63, w = t >> 6;
  const int l15 = lane & 15, lhi = lane >> 4;
  const int bx = blockIdx.x & 511;
  const int ph = ((blockIdx.x >> 8) & 1) * 16;
  const int xcd = bx & 7, idx = bx >> 3;
  const int kp = xcd >> 1;
  const int m = (idx << 1) | (xcd & 1);
  const int mBase = m * 64;
  const int kpBase = kp * 2048;
  const int waveM = (w >> 2) * 32;
  const int waveN = (w & 3) * (BN / 4);

  f32x4 acc[FR][FC];
#pragma unroll
  for (int a = 0; a < FR; ++a)
#pragma unroll
    for (int b = 0; b < FC; ++b) acc[a][b] = (f32x4){0.f, 0.f, 0.f, 0.f};

  auto issueAB = [&](int tt, int buf) {
    const int k0 = kpBase + ((tt + ph) & (NSTEP - 1)) * BK;
    {
      int L = t * 16;
      int row = L >> 7;
      int kb = (L & 127) ^ ((row & 7) << 4);
      gld16((const char*)Av + ((size_t)(mBase + row) << 14) + ((size_t)k0 << 1) + kb,
            (char*)(sA + buf * 4096) + L);
    }
#pragma unroll
    for (int i = 0; i < NB; ++i) {
      int L = i * 8192 + t * 16;
      int n = L >> 7;
      int kb = (L & 127) ^ ((n & 7) << 4);
      gld16((const char*)Bt + ((size_t)n << 14) + ((size_t)k0 << 1) + kb,
            (char*)(sB + buf * (BN * 64)) + L);
    }
  };

  issueAB(0, 0);
  for (int tt = 0; tt < NSTEP; ++tt) {
    const int buf = tt & 1;
    if (tt + 1 < NSTEP) {
      issueAB(tt + 1, buf ^ 1);
      waitvm<NI>();
    } else {
      waitvm<0>();
    }
    __builtin_amdgcn_s_barrier();
    const u16* pa = sA + buf * 4096;
    const u16* pb = sB + buf * (BN * 64);
#pragma unroll
    for (int ks = 0; ks < 2; ++ks) {
      bf16x8 av[FR], bv[FC];
#pragma unroll
      for (int fr = 0; fr < FR; ++fr) {
        int row = waveM + fr * 16 + l15;
        int off = row * 128 + ((ks * 64 + lhi * 16) ^ ((row & 7) << 4));
        av[fr] = *(const bf16x8*)((const char*)pa + off);
      }
#pragma unroll
      for (int fc = 0; fc < FC; ++fc) {
        int n = waveN + fc * 16 + l15;
        int off = n * 128 + ((ks * 64 + lhi * 16) ^ ((n & 7) << 4));
        bv[fc] = *(const bf16x8*)((const char*)pb + off);
      }
#pragma unroll
      for (int fr = 0; fr < FR; ++fr)
#pragma unroll
        for (int fc = 0; fc < FC; ++fc)
          acc[fr][fc] = __builtin_amdgcn_mfma_f32_16x16x32_bf16(
              av[fr], bv[fc], acc[fr][fc], 0, 0, 0);
    }
    __builtin_amdgcn_s_barrier();
  }

  if (PACK) {
    unsigned* pp = (unsigned*)part + (size_t)kp * 8192 * 128 + (size_t)mBase * 128;
#pragma unroll
    for (int fr = 0; fr < FR; ++fr)
#pragma unroll
      for (int fcp = 0; fcp < FC / 2; ++fcp) {
        int g = (waveN >> 5) + fcp;
        int r0 = waveM + fr * 16 + lhi * 4;
#pragma unroll
        for (int j = 0; j < 4; ++j)
          pp[(size_t)(r0 + j) * 128 + g * 16 + l15] =
              cvtpk(acc[fr][2 * fcp][j], acc[fr][2 * fcp + 1][j]);
      }
  } else {
    float* pf = (float*)part + (size_t)kp * 8192 * BN + (size_t)mBase * BN;
#pragma unroll
    for (int fr = 0; fr < FR; ++fr)
#pragma unroll
      for (int fc = 0; fc < FC; ++fc) {
        int col = waveN + fc * 16 + l15;
        int r0 = waveM + fr * 16 + lhi * 4;
#pragma unroll
        for (int j = 0; j < 4; ++j)
          pf[(size_t)(r0 + j) * BN + col] = acc[fr][fc][j];
      }
  }
}

// Small GEMM: M=8192, K=256, A bf16 row-major, Bt [BN][256] bf16 (LDS-staged).
// OMODE 0: f32 row-major; 1: bf16 transposed Ct[(colBlk+col)][8192]; 2: bf16 row-major
template <int BN, int EPI, int OMODE>
__global__ __launch_bounds__(256)
void sgemm_k(const u16* __restrict__ Abf, const u16* __restrict__ Bt,
             float* __restrict__ C, int ldc, u16* __restrict__ Ct) {
  __shared__ u16 sA[32 * 256];
  __shared__ u16 sB[BN * 256];
  const int t = threadIdx.x, lane = t & 63, w = t >> 6;
  const int rowBase = blockIdx.x * 32;
  const u16* bt = Bt + (size_t)blockIdx.y * BN * 256;
  const int colBlk = blockIdx.y * BN;

#pragma unroll
  for (int i = 0; i < 4; ++i) {
    int lin = ((w * 4 + i) << 10) + (lane << 4);
    int row = lin >> 9;
    int kb = (lin & 511) ^ ((row & 7) << 4);
    const char* g = (const char*)Abf + ((size_t)(rowBase + row) << 9) + kb;
    gld16(g, (char*)sA + ((w * 4 + i) << 10));
  }
#pragma unroll
  for (int i = 0; i < BN / 8; ++i) {
    int lin = ((w * (BN / 8) + i) << 10) + (lane << 4);
    int n = lin >> 9;
    int kb = (lin & 511) ^ ((n & 7) << 4);
    const char* g = (const char*)bt + ((size_t)n << 9) + kb;
    gld16(g, (char*)sB + ((w * (BN / 8) + i) << 10));
  }
  __syncthreads();

  constexpr int FC = BN / 32;
  const int waveM = (w & 1) * 16;
  const int waveN = (w >> 1) * (BN / 2);
  f32x4 acc[FC];
#pragma unroll
  for (int b = 0; b < FC; ++b) acc[b] = (f32x4){0.f, 0.f, 0.f, 0.f};

#pragma unroll
  for (int ks = 0; ks < 8; ++ks) {
    int row = waveM + (lane & 15);
    int offA = (row * 512 + ks * 64 + ((lane >> 4) * 16)) ^ ((row & 7) << 4);
    bf16x8 av = *(const bf16x8*)((const char*)sA + offA);
#pragma unroll
    for (int fc = 0; fc < FC; ++fc) {
      int n = waveN + fc * 16 + (lane & 15);
      int offB = (n * 512 + ks * 64 + ((lane >> 4) * 16)) ^ ((n & 7) << 4);
      bf16x8 bv = *(const bf16x8*)((const char*)sB + offB);
      acc[fc] = __builtin_amdgcn_mfma_f32_16x16x32_bf16(av, bv, acc[fc], 0, 0, 0);
    }
  }

#pragma unroll
  for (int fc = 0; fc < FC; ++fc) {
    int col = waveN + fc * 16 + (lane & 15);
    int r0 = rowBase + waveM + ((lane >> 4) << 2);
    float o[4];
#pragma unroll
    for (int j = 0; j < 4; ++j) {
      float xv = acc[fc][j];
      if (EPI == 1) xv = fmaxf(xv, 0.f);
      if (EPI == 2) xv = (xv > 0.f) ? xv : 0.2f * xv;
      o[j] = xv;
    }
    if (OMODE == 1) {
      uint2 q; q.x = pk2(o[0], o[1]); q.y = pk2(o[2], o[3]);
      *(uint2*)(Ct + (size_t)(colBlk + col) * 8192 + r0) = q;
    } else if (OMODE == 2) {
#pragma unroll
      for (int j = 0; j < 4; ++j)
        Ct[(size_t)(r0 + j) * ldc + colBlk + col] = f2bf(o[j]);
    } else {
#pragma unroll
      for (int j = 0; j < 4; ++j)
        C[(size_t)(r0 + j) * ldc + colBlk + col] = o[j];
    }
  }
}

// reduce 4 packed-bf16 partials. MODE 1: -dd[row]*xbf -> bf16; MODE 2: relu(+bias)->bf16
template <int MODE>
__global__ __launch_bounds__(256)
void reduce4p_k(const unsigned* __restrict__ part, const float* __restrict__ bias,
                const float* __restrict__ dd, const u16* __restrict__ xbf,
                u16* __restrict__ Cb) {
  const int tid = threadIdx.x;
  const int row = blockIdx.x * 2 + (tid >> 7);
  const int uc = tid & 127;
  const size_t S = (size_t)8192 * 128;
  const size_t b = (size_t)row * 128 + uc;
  float slo = 0.f, shi = 0.f;
#pragma unroll
  for (int p = 0; p < 4; ++p) {
    unsigned v = part[b + (size_t)p * S];
    slo += bf2f((u16)(v & 0xffff));
    shi += bf2f((u16)(v >> 16));
  }
  const int clo = (uc & 15) + ((uc >> 4) << 5), chi = clo + 16;
  if (MODE == 1) {
    float d = dd[row];
    slo -= d * bf2f(xbf[(size_t)row * 256 + clo]);
    shi -= d * bf2f(xbf[(size_t)row * 256 + chi]);
  } else {
    slo = fmaxf(slo + bias[clo], 0.f);
    shi = fmaxf(shi + bias[chi], 0.f);
  }
  Cb[(size_t)row * 256 + clo] = f2bf(slo);
  Cb[(size_t)row * 256 + chi] = f2bf(shi);
}

// fused: base=relu(sum(adj_f partials)+bp); lp=(g+1)*base+beta; L2-normalize;
// xin_bf = bf16(0.5*(x+lp/nrm)). One row per block, 128 threads.
__global__ __launch_bounds__(128)
void fuse_red_k(const unsigned* __restrict__ part, const float* __restrict__ bp,
                const u16* __restrict__ gbuf, const u16* __restrict__ xbf,
                u16* __restrict__ xin_bf) {
  const int row = blockIdx.x, uc = threadIdx.x;
  const size_t S = (size_t)8192 * 128;
  const size_t b = (size_t)row * 128 + uc;
  float slo = 0.f, shi = 0.f;
#pragma unroll
  for (int p = 0; p < 4; ++p) {
    unsigned v = part[b + (size_t)p * S];
    slo += bf2f((u16)(v & 0xffff));
    shi += bf2f((u16)(v >> 16));
  }
  const int clo = (uc & 15) + ((uc >> 4) << 5), chi = clo + 16;
  float baselo = fmaxf(slo + bp[clo], 0.f);
  float basehi = fmaxf(shi + bp[chi], 0.f);
  float glo = bf2f(gbuf[(size_t)row * 512 + clo]);
  float ghi = bf2f(gbuf[(size_t)row * 512 + chi]);
  float btlo = bf2f(gbuf[(size_t)row * 512 + 256 + clo]);
  float bthi = bf2f(gbuf[(size_t)row * 512 + 256 + chi]);
  float lplo = (glo + 1.f) * baselo + btlo;
  float lphi = (ghi + 1.f) * basehi + bthi;
  float ss = lplo * lplo + lphi * lphi;
#pragma unroll
  for (int off = 32; off >= 1; off >>= 1) ss += __shfl_xor(ss, off);
  __shared__ float wsum[2];
  if ((uc & 63) == 0) wsum[uc >> 6] = ss;
  __syncthreads();
  float inv = 1.f / fmaxf(sqrtf(wsum[0] + wsum[1]), 1e-12f);
  xin_bf[(size_t)row * 256 + clo] =
      f2bf(0.5f * (bf2f(xbf[(size_t)row * 256 + clo]) + lplo * inv));
  xin_bf[(size_t)row * 256 + chi] =
      f2bf(0.5f * (bf2f(xbf[(size_t)row * 256 + chi]) + lphi * inv));
}

// reduce logits partials [4][8192][64] f32 + b2, then log_softmax over 40 cols
__global__ __launch_bounds__(256)
void reduce_lsm_k(const float* __restrict__ part, const float* __restrict__ b2,
                  float* __restrict__ out) {
  const int t = threadIdx.x, lane = t & 63, w = t >> 6;
  const int row = blockIdx.x * 4 + w;
  const size_t i = (size_t)row * 64 + lane;
  const size_t S = (size_t)8192 * 64;
  float v = 0.f;
#pragma unroll
  for (int p = 0; p < 4; ++p) v += part[i + (size_t)p * S];
  v = (lane < 40) ? v + b2[lane] : -1e30f;
  float mx = v;
#pragma unroll
  for (int off = 32; off >= 1; off >>= 1) mx = fmaxf(mx, __shfl_xor(mx, off));
  float e = (lane < 40) ? expf(v - mx) : 0.f;
#pragma unroll
  for (int off = 32; off >= 1; off >>= 1) e += __shfl_xor(e, off);
  float ls = mx + logf(e);
  if (lane < 40) out[(size_t)row * 40 + lane] = v - ls;
}

extern "C" void kernel_launch(void* const* d_in, const int* in_sizes, int n_in,
                              void* d_out, int out_size, void* d_ws, size_t ws_size,
                              hipStream_t stream) {
  const float* x = (const float*)d_in[0];
  const float* adj_f = (const float*)d_in[1];
  const float* adj_a = (const float*)d_in[2];
  const float* Wp = (const float*)d_in[3];
  const float* bp = (const float*)d_in[4];
  const float* Wg = (const float*)d_in[5];
  const float* Wb = (const float*)d_in[6];
  const float* W1 = (const float*)d_in[7];
  const float* b1 = (const float*)d_in[8];
  const float* W2 = (const float*)d_in[9];
  const float* b2 = (const float*)d_in[10];
  float* out = (float*)d_out;

  char* ws = (char*)d_ws;
  size_t off = 0;
  auto alloc = [&](size_t bytes) {
    char* p = ws + off;
    off += (bytes + 255) & ~(size_t)255;
    return p;
  };
  unsigned* partA = (unsigned*)alloc((size_t)4 * 8192 * 128 * 4);  // 16 MB (adj_f)
  unsigned* partB = (unsigned*)alloc((size_t)4 * 8192 * 128 * 4);  // 16 MB (neigh/h/logits)
  float* partBF = (float*)partB;
  u16* featT = (u16*)alloc((size_t)256 * 8192 * 2);
  u16* featT64 = (u16*)alloc((size_t)64 * 8192 * 2);
  u16* xT = (u16*)alloc((size_t)256 * 8192 * 2);
  u16* xbf = (u16*)alloc((size_t)8192 * 256 * 2);
  u16* xin_bf = (u16*)alloc((size_t)8192 * 256 * 2);
  u16* neigh_bf = (u16*)alloc((size_t)8192 * 256 * 2);
  u16* h_bf = (u16*)alloc((size_t)8192 * 256 * 2);
  u16* gbuf = (u16*)alloc((size_t)8192 * 512 * 2);
  u16* WpT = (u16*)alloc(256 * 256 * 2);
  u16* WgbT = (u16*)alloc(512 * 256 * 2);
  u16* W1T = (u16*)alloc(256 * 256 * 2);
  u16* W2T = (u16*)alloc(64 * 256 * 2);
  float* dd = (float*)alloc(8192 * 4);

  const size_t adjBytes = (size_t)8192 * 8192 * 2;
  bool useBf = (ws_size >= off + adjBytes + 256);
  u16* adj_bf = useBf ? (u16*)alloc(adjBytes) : nullptr;

  dim3 b256(256), b512(512);
  prep_w_k<<<dim3(8, 8, 5), b256, 0, stream>>>(Wp, Wg, Wb, W1, W2, WpT, WgbT, W1T, W2T);
  prep_x_k<<<dim3(8, 256), b256, 0, stream>>>(x, adj_a, xT, xbf, dd);

  // t1^T = (x @ Wp)^T
  sgemm_k<128, 0, 1><<<dim3(256, 2), b256, 0, stream>>>(xbf, WpT, nullptr, 0, featT);
  // merged: adj_f partials (blocks 0-511) + neigh partials/adj_bf (512-1023)
  if (useBf)
    bgemm2_k<true><<<1024, b512, 0, stream>>>(adj_f, featT, partA, adj_a, xT, partB, adj_bf);
  else
    bgemm2_k<false><<<1024, b512, 0, stream>>>(adj_f, featT, partA, adj_a, xT, partB, nullptr);
  reduce4p_k<1><<<4096, b256, 0, stream>>>(partB, nullptr, dd, xbf, neigh_bf);
  // gamma|beta = leaky(neigh @ [Wg|Wb]) -> gbuf bf16 [8192][512]
  sgemm_k<128, 2, 2><<<dim3(256, 4), b256, 0, stream>>>(neigh_bf, WgbT, nullptr, 512, gbuf);
  // fused: base-reduce(adj_f partials) + prompt-mix + normalize -> xin_bf
  fuse_red_k<<<8192, dim3(128), 0, stream>>>(partA, bp, gbuf, xbf, xin_bf);
  // t2^T = (x_in @ W1)^T
  sgemm_k<128, 0, 1><<<dim3(256, 2), b256, 0, stream>>>(xin_bf, W1T, nullptr, 0, featT);
  // h = relu(adj_a @ t2 + b1)  (adj_bf L3-hot)
  if (useBf)
    bgemm_abf_k<256, true><<<512, b512, 0, stream>>>(adj_bf, featT, partB);
  else
    bgemm_f32_k<256, true><<<512, b512, 0, stream>>>(adj_a, featT, partB);
  reduce4p_k<2><<<4096, b256, 0, stream>>>(partB, b1, nullptr, nullptr, h_bf);
  // t3^T = (h @ W2)^T
  sgemm_k<64, 0, 1><<<dim3(256, 1), b256, 0, stream>>>(h_bf, W2T, nullptr, 0, featT64);
  // logits partials (f32) then fused reduce + log_softmax
  if (useBf)
    bgemm_abf_k<64, false><<<512, b512, 0, stream>>>(adj_bf, featT64, partB);
  else
    bgemm_f32_k<64, false><<<512, b512, 0, stream>>>(adj_a, featT64, partB);
  reduce_lsm_k<<<2048, b256, 0, stream>>>(partBF, b2, out);
}

// Round 18
// 295.179 us; speedup vs baseline: 1.0587x; 1.0587x over previous
//
#include <hip/hip_runtime.h>

typedef unsigned short u16;
typedef __attribute__((ext_vector_type(8))) short bf16x8;
typedef __attribute__((ext_vector_type(4))) float f32x4;

__device__ __forceinline__ u16 f2bf(float f) {
  union { float f; unsigned u; } v; v.f = f;
  unsigned r = v.u + 0x7FFFu + ((v.u >> 16) & 1u);
  return (u16)(r >> 16);
}
__device__ __forceinline__ float bf2f(u16 h) {
  union { unsigned u; float f; } v; v.u = ((unsigned)h) << 16; return v.f;
}
__device__ __forceinline__ unsigned pk2(float a, float b) {
  return (unsigned)f2bf(a) | ((unsigned)f2bf(b) << 16);
}
__device__ __forceinline__ unsigned cvtpk(float a, float b) {
  unsigned r;
  asm("v_cvt_pk_bf16_f32 %0, %1, %2" : "=v"(r) : "v"(a), "v"(b));
  return r;
}
__device__ __forceinline__ void gld16(const void* g, void* l) {
  __builtin_amdgcn_global_load_lds(
      (const __attribute__((address_space(1))) unsigned int*)g,
      (__attribute__((address_space(3))) unsigned int*)l, 16, 0, 0);
}
// LDS sub-row addressing: logical 256B rows stored as 2x128B sub-rows,
// swizzle keyed on sub&7.
__device__ __forceinline__ int subOff(int row, int kh, int xh) {
  int sub = row * 2 + kh;
  return sub * 128 + (xh ^ ((sub & 7) << 4));
}

// All weight transposes in one kernel. in [256][C] f32 -> out [Cout][256] bf16.
__global__ __launch_bounds__(256)
void prep_w_k(const float* __restrict__ Wp, const float* __restrict__ Wg,
              const float* __restrict__ Wb, const float* __restrict__ W1,
              const float* __restrict__ W2, u16* __restrict__ WpT,
              u16* __restrict__ WgbT, u16* __restrict__ W1T,
              u16* __restrict__ W2T) {
  int z = blockIdx.z;
  const float* in; u16* out; int C = 256;
  if (z == 0) { in = Wp; out = WpT; }
  else if (z == 1) { in = Wg; out = WgbT; }
  else if (z == 2) { in = Wb; out = WgbT + 65536; }
  else if (z == 3) { in = W1; out = W1T; }
  else { in = W2; out = W2T; C = 40; if (blockIdx.x >= 2) return; }
  __shared__ float tile[32][33];
  int tj = blockIdx.x * 32, ti = blockIdx.y * 32;
  int t = threadIdx.x, c = t & 31, r0 = t >> 5;
#pragma unroll
  for (int p = 0; p < 4; ++p) {
    int r = r0 + p * 8;
    tile[r][c] = (tj + c < C) ? in[(size_t)(ti + r) * C + (tj + c)] : 0.f;
  }
  __syncthreads();
#pragma unroll
  for (int p = 0; p < 4; ++p) {
    int rr = r0 + p * 8;
    out[(size_t)(tj + rr) * 256 + (ti + c)] = f2bf(tile[c][rr]);
  }
}

// x [8192][256] f32 -> xT [256][8192] bf16 and xbf [8192][256] bf16.
// Blocks with tj==0 also extract dd[row] = bf16-rounded adj_a[row][row].
__global__ __launch_bounds__(256)
void prep_x_k(const float* __restrict__ x, const float* __restrict__ adj,
              u16* __restrict__ xT, u16* __restrict__ xbf,
              float* __restrict__ dd) {
  __shared__ float tile[32][33];
  int tj = blockIdx.x * 32, ti = blockIdx.y * 32;
  int t = threadIdx.x, c = t & 31, r0 = t >> 5;
#pragma unroll
  for (int p = 0; p < 4; ++p) {
    int r = r0 + p * 8;
    float v = x[(size_t)(ti + r) * 256 + (tj + c)];
    tile[r][c] = v;
    xbf[(size_t)(ti + r) * 256 + (tj + c)] = f2bf(v);
  }
  if (tj == 0 && t < 32) {
    int r = ti + t;
    dd[r] = bf2f(f2bf(adj[(size_t)r * 8193]));
  }
  __syncthreads();
#pragma unroll
  for (int p = 0; p < 4; ++p) {
    int rr = r0 + p * 8;
    xT[(size_t)(tj + rr) * 8192 + (ti + c)] = f2bf(tile[c][rr]);
  }
}

// Dual fp32 big GEMM: BM=64, BK=128, split-K=4 (KP=2048, 16 steps), 8 waves,
// reg-staged bf16 A (16KB) + gld16 B (64KB), 80KB -> 2 blocks/CU. Grid 1024:
// blocks 0-511 adj_f->part1, 512-1023 adj_a->part2 (+bf16 writeback).
// ANTI-PHASE: blocks with (blockIdx>>8)&1 rotate the K-step sequence by 8 so
// co-resident blocks overlap load phase with compute phase.
template <bool WRB2>
__global__ __launch_bounds__(512, 2)
void bgemm2_k(const float* __restrict__ A1, const u16* __restrict__ Bt1,
              unsigned* __restrict__ part1, const float* __restrict__ A2,
              const u16* __restrict__ Bt2, unsigned* __restrict__ part2,
              u16* __restrict__ Aout) {
  constexpr int BM = 64;
  constexpr int KP = 2048;
  constexpr int BK = 128;
  constexpr int NSTEP = KP / BK;  // 16
  constexpr int NB = 8;
  constexpr int FR = 2;
  constexpr int FC = 4;

  __shared__ u16 sA[BM * BK];     // 16 KB
  __shared__ u16 sB[256 * BK];    // 64 KB
  const int t = threadIdx.x, lane = t & 63, w = t >> 6;
  const int l15 = lane & 15, lhi = lane >> 4;
  const bool second = blockIdx.x >= 512;
  const float* Av = second ? A2 : A1;
  const u16* Bt = second ? Bt2 : Bt1;
  unsigned* part = second ? part2 : part1;
  const bool wrb = second && WRB2;
  const int bx = blockIdx.x & 511;
  const int ph = ((blockIdx.x >> 8) & 1) * (NSTEP / 2);
  const int xcd = bx & 7, idx = bx >> 3;
  const int kp = xcd >> 1;
  const int m = (idx << 1) | (xcd & 1);  // 0..127
  const int mBase = m * BM;
  const int kpBase = kp * KP;
  const int waveM = (w >> 2) * 32;
  const int waveN = (w & 3) * 64;

  f32x4 acc[FR][FC];
#pragma unroll
  for (int a = 0; a < FR; ++a)
#pragma unroll
    for (int b = 0; b < FC; ++b) acc[a][b] = (f32x4){0.f, 0.f, 0.f, 0.f};

  const int rA = t >> 3, qA = t & 7;
  const int khA = qA >> 2;
  const int xhA = (qA & 3) * 32;

  for (int su = 0; su < NSTEP; ++su) {
    const int st = (su + ph) & (NSTEP - 1);
    const int k0 = kpBase + st * BK;
    // ---- B stage (async direct-to-LDS), pre-swizzled source ----
#pragma unroll
    for (int i = 0; i < NB; ++i) {
      int L = i * 8192 + t * 16;
      int sub = L >> 7;
      int n = sub >> 1, kh = sub & 1;
      int kb = (L & 127) ^ ((sub & 7) << 4);
      gld16((const char*)Bt + ((size_t)n << 14) + ((size_t)k0 << 1) + kh * 128 + kb,
            (char*)sB + L);
    }
    // ---- A stage (fp32 -> bf16 reg-staged) ----
    {
      const float* gp = Av + ((size_t)(mBase + rA) << 13) + k0 + qA * 16;
      float4 f0 = *(const float4*)gp;
      float4 f1 = *(const float4*)(gp + 4);
      float4 f2 = *(const float4*)(gp + 8);
      float4 f3 = *(const float4*)(gp + 12);
      uint4 q0, q1;
      q0.x = cvtpk(f0.x, f0.y); q0.y = cvtpk(f0.z, f0.w);
      q0.z = cvtpk(f1.x, f1.y); q0.w = cvtpk(f1.z, f1.w);
      q1.x = cvtpk(f2.x, f2.y); q1.y = cvtpk(f2.z, f2.w);
      q1.z = cvtpk(f3.x, f3.y); q1.w = cvtpk(f3.z, f3.w);
      *(uint4*)((char*)sA + subOff(rA, khA, xhA)) = q0;
      *(uint4*)((char*)sA + subOff(rA, khA, xhA + 16)) = q1;
      if (wrb) {
        u16* dst = Aout + ((size_t)(mBase + rA) << 13) + k0 + qA * 16;
        *(uint4*)dst = q0;
        *(uint4*)(dst + 8) = q1;
      }
    }
    __syncthreads();
    // ---- compute: 4 k-slices of 32 ----
#pragma unroll
    for (int ks = 0; ks < 4; ++ks) {
      const int kh = ks >> 1;
      const int xh = (ks & 1) * 64 + lhi * 16;
      bf16x8 av[FR], bv[FC];
#pragma unroll
      for (int fr = 0; fr < FR; ++fr) {
        int row = waveM + fr * 16 + l15;
        av[fr] = *(const bf16x8*)((const char*)sA + subOff(row, kh, xh));
      }
#pragma unroll
      for (int fc = 0; fc < FC; ++fc) {
        int n = waveN + fc * 16 + l15;
        bv[fc] = *(const bf16x8*)((const char*)sB + subOff(n, kh, xh));
      }
#pragma unroll
      for (int fr = 0; fr < FR; ++fr)
#pragma unroll
        for (int fc = 0; fc < FC; ++fc)
          acc[fr][fc] = __builtin_amdgcn_mfma_f32_16x16x32_bf16(
              av[fr], bv[fc], acc[fr][fc], 0, 0, 0);
    }
    __syncthreads();
  }

  unsigned* pp = part + (size_t)kp * 8192 * 128 + (size_t)mBase * 128;
#pragma unroll
  for (int fr = 0; fr < FR; ++fr)
#pragma unroll
    for (int fcp = 0; fcp < FC / 2; ++fcp) {
      int g = (waveN >> 5) + fcp;
      int r0 = waveM + fr * 16 + lhi * 4;
#pragma unroll
      for (int j = 0; j < 4; ++j)
        pp[(size_t)(r0 + j) * 128 + g * 16 + l15] =
            cvtpk(acc[fr][2 * fcp][j], acc[fr][2 * fcp + 1][j]);
    }
}

// Single big GEMM (bf16 A or fp32 fallback), with anti-phase rotation.
template <int BN, bool ABF, bool WRB, bool PACK>
__global__ __launch_bounds__(512, 2)
void bgemm_k(const void* __restrict__ Av, const u16* __restrict__ Bt,
             void* __restrict__ part, u16* __restrict__ Aout) {
  constexpr int BM = 64;
  constexpr int KP = 2048;
  constexpr int BK = 128;
  constexpr int NSTEP = KP / BK;  // 16
  constexpr int NB = BN / 32;
  constexpr int FR = 2;
  constexpr int FC = BN / 64;

  __shared__ u16 sA[BM * BK];
  __shared__ u16 sB[BN * BK];
  const int t = threadIdx.x, lane = t & 63, w = t >> 6;
  const int l15 = lane & 15, lhi = lane >> 4;
  const int xcd = blockIdx.x & 7, idx = blockIdx.x >> 3;
  const int ph = ((blockIdx.x >> 8) & 1) * (NSTEP / 2);
  const int kp = xcd >> 1;
  const int m = (idx << 1) | (xcd & 1);
  const int mBase = m * BM;
  const int kpBase = kp * KP;
  const int waveM = (w >> 2) * 32;
  const int waveN = (w & 3) * (BN / 4);

  f32x4 acc[FR][FC];
#pragma unroll
  for (int a = 0; a < FR; ++a)
#pragma unroll
    for (int b = 0; b < FC; ++b) acc[a][b] = (f32x4){0.f, 0.f, 0.f, 0.f};

  const int rA = t >> 3, qA = t & 7;
  const int khA = qA >> 2;
  const int xhA = (qA & 3) * 32;

  for (int su = 0; su < NSTEP; ++su) {
    const int st = (su + ph) & (NSTEP - 1);
    const int k0 = kpBase + st * BK;
#pragma unroll
    for (int i = 0; i < NB; ++i) {
      int L = i * 8192 + t * 16;
      int sub = L >> 7;
      int n = sub >> 1, kh = sub & 1;
      int kb = (L & 127) ^ ((sub & 7) << 4);
      gld16((const char*)Bt + ((size_t)n << 14) + ((size_t)k0 << 1) + kh * 128 + kb,
            (char*)sB + L);
    }
    if (ABF) {
#pragma unroll
      for (int i = 0; i < 2; ++i) {
        int L = i * 8192 + t * 16;
        int sub = L >> 7;
        int row = sub >> 1, kh = sub & 1;
        int kb = (L & 127) ^ ((sub & 7) << 4);
        gld16((const char*)Av + ((size_t)(mBase + row) << 14) + ((size_t)k0 << 1) +
                  kh * 128 + kb,
              (char*)sA + L);
      }
    } else {
      const float* gp = (const float*)Av + ((size_t)(mBase + rA) << 13) + k0 + qA * 16;
      float4 f0 = *(const float4*)gp;
      float4 f1 = *(const float4*)(gp + 4);
      float4 f2 = *(const float4*)(gp + 8);
      float4 f3 = *(const float4*)(gp + 12);
      uint4 q0, q1;
      q0.x = cvtpk(f0.x, f0.y); q0.y = cvtpk(f0.z, f0.w);
      q0.z = cvtpk(f1.x, f1.y); q0.w = cvtpk(f1.z, f1.w);
      q1.x = cvtpk(f2.x, f2.y); q1.y = cvtpk(f2.z, f2.w);
      q1.z = cvtpk(f3.x, f3.y); q1.w = cvtpk(f3.z, f3.w);
      *(uint4*)((char*)sA + subOff(rA, khA, xhA)) = q0;
      *(uint4*)((char*)sA + subOff(rA, khA, xhA + 16)) = q1;
      if (WRB) {
        u16* dst = Aout + ((size_t)(mBase + rA) << 13) + k0 + qA * 16;
        *(uint4*)dst = q0;
        *(uint4*)(dst + 8) = q1;
      }
    }
    __syncthreads();
#pragma unroll
    for (int ks = 0; ks < 4; ++ks) {
      const int kh = ks >> 1;
      const int xh = (ks & 1) * 64 + lhi * 16;
      bf16x8 av[FR], bv[FC];
#pragma unroll
      for (int fr = 0; fr < FR; ++fr) {
        int row = waveM + fr * 16 + l15;
        av[fr] = *(const bf16x8*)((const char*)sA + subOff(row, kh, xh));
      }
#pragma unroll
      for (int fc = 0; fc < FC; ++fc) {
        int n = waveN + fc * 16 + l15;
        bv[fc] = *(const bf16x8*)((const char*)sB + subOff(n, kh, xh));
      }
#pragma unroll
      for (int fr = 0; fr < FR; ++fr)
#pragma unroll
        for (int fc = 0; fc < FC; ++fc)
          acc[fr][fc] = __builtin_amdgcn_mfma_f32_16x16x32_bf16(
              av[fr], bv[fc], acc[fr][fc], 0, 0, 0);
    }
    __syncthreads();
  }

  if (PACK) {
    unsigned* pp = (unsigned*)part + (size_t)kp * 8192 * 128 + (size_t)mBase * 128;
#pragma unroll
    for (int fr = 0; fr < FR; ++fr)
#pragma unroll
      for (int fcp = 0; fcp < FC / 2; ++fcp) {
        int g = (waveN >> 5) + fcp;
        int r0 = waveM + fr * 16 + lhi * 4;
#pragma unroll
        for (int j = 0; j < 4; ++j)
          pp[(size_t)(r0 + j) * 128 + g * 16 + l15] =
              cvtpk(acc[fr][2 * fcp][j], acc[fr][2 * fcp + 1][j]);
      }
  } else {
    float* pp = (float*)part + (size_t)kp * 8192 * BN + (size_t)mBase * BN;
#pragma unroll
    for (int fr = 0; fr < FR; ++fr)
#pragma unroll
      for (int fc = 0; fc < FC; ++fc) {
        int col = waveN + fc * 16 + l15;
        int r0 = waveM + fr * 16 + lhi * 4;
#pragma unroll
        for (int j = 0; j < 4; ++j)
          pp[(size_t)(r0 + j) * BN + col] = acc[fr][fc][j];
      }
  }
}

// Small GEMM: M=8192, K=256, A bf16 row-major, Bt [BN][256] bf16 (LDS-staged).
// OMODE 0: f32 row-major; 1: bf16 transposed Ct[(colBlk+col)][8192]; 2: bf16 row-major
template <int BN, int EPI, int OMODE>
__global__ __launch_bounds__(256)
void sgemm_k(const u16* __restrict__ Abf, const u16* __restrict__ Bt,
             float* __restrict__ C, int ldc, u16* __restrict__ Ct) {
  __shared__ u16 sA[32 * 256];
  __shared__ u16 sB[BN * 256];
  const int t = threadIdx.x, lane = t & 63, w = t >> 6;
  const int rowBase = blockIdx.x * 32;
  const u16* bt = Bt + (size_t)blockIdx.y * BN * 256;
  const int colBlk = blockIdx.y * BN;

#pragma unroll
  for (int i = 0; i < 4; ++i) {
    int lin = ((w * 4 + i) << 10) + (lane << 4);
    int row = lin >> 9;
    int kb = (lin & 511) ^ ((row & 7) << 4);
    const char* g = (const char*)Abf + ((size_t)(rowBase + row) << 9) + kb;
    gld16(g, (char*)sA + ((w * 4 + i) << 10));
  }
#pragma unroll
  for (int i = 0; i < BN / 8; ++i) {
    int lin = ((w * (BN / 8) + i) << 10) + (lane << 4);
    int n = lin >> 9;
    int kb = (lin & 511) ^ ((n & 7) << 4);
    const char* g = (const char*)bt + ((size_t)n << 9) + kb;
    gld16(g, (char*)sB + ((w * (BN / 8) + i) << 10));
  }
  __syncthreads();

  constexpr int FC = BN / 32;
  const int waveM = (w & 1) * 16;
  const int waveN = (w >> 1) * (BN / 2);
  f32x4 acc[FC];
#pragma unroll
  for (int b = 0; b < FC; ++b) acc[b] = (f32x4){0.f, 0.f, 0.f, 0.f};

#pragma unroll
  for (int ks = 0; ks < 8; ++ks) {
    int row = waveM + (lane & 15);
    int offA = (row * 512 + ks * 64 + ((lane >> 4) * 16)) ^ ((row & 7) << 4);
    bf16x8 av = *(const bf16x8*)((const char*)sA + offA);
#pragma unroll
    for (int fc = 0; fc < FC; ++fc) {
      int n = waveN + fc * 16 + (lane & 15);
      int offB = (n * 512 + ks * 64 + ((lane >> 4) * 16)) ^ ((n & 7) << 4);
      bf16x8 bv = *(const bf16x8*)((const char*)sB + offB);
      acc[fc] = __builtin_amdgcn_mfma_f32_16x16x32_bf16(av, bv, acc[fc], 0, 0, 0);
    }
  }

#pragma unroll
  for (int fc = 0; fc < FC; ++fc) {
    int col = waveN + fc * 16 + (lane & 15);
    int r0 = rowBase + waveM + ((lane >> 4) << 2);
    float o[4];
#pragma unroll
    for (int j = 0; j < 4; ++j) {
      float xv = acc[fc][j];
      if (EPI == 1) xv = fmaxf(xv, 0.f);
      if (EPI == 2) xv = (xv > 0.f) ? xv : 0.2f * xv;
      o[j] = xv;
    }
    if (OMODE == 1) {
      uint2 q; q.x = pk2(o[0], o[1]); q.y = pk2(o[2], o[3]);
      *(uint2*)(Ct + (size_t)(colBlk + col) * 8192 + r0) = q;
    } else if (OMODE == 2) {
#pragma unroll
      for (int j = 0; j < 4; ++j)
        Ct[(size_t)(r0 + j) * ldc + colBlk + col] = f2bf(o[j]);
    } else {
#pragma unroll
      for (int j = 0; j < 4; ++j)
        C[(size_t)(r0 + j) * ldc + colBlk + col] = o[j];
    }
  }
}

// reduce 4 packed-bf16 partials. MODE 1: -dd[row]*xbf -> bf16; MODE 2: relu(+bias)->bf16
template <int MODE>
__global__ __launch_bounds__(256)
void reduce4p_k(const unsigned* __restrict__ part, const float* __restrict__ bias,
                const float* __restrict__ dd, const u16* __restrict__ xbf,
                u16* __restrict__ Cb) {
  const int tid = threadIdx.x;
  const int row = blockIdx.x * 2 + (tid >> 7);
  const int uc = tid & 127;
  const size_t S = (size_t)8192 * 128;
  const size_t b = (size_t)row * 128 + uc;
  float slo = 0.f, shi = 0.f;
#pragma unroll
  for (int p = 0; p < 4; ++p) {
    unsigned v = part[b + (size_t)p * S];
    slo += bf2f((u16)(v & 0xffff));
    shi += bf2f((u16)(v >> 16));
  }
  const int clo = (uc & 15) + ((uc >> 4) << 5), chi = clo + 16;
  if (MODE == 1) {
    float d = dd[row];
    slo -= d * bf2f(xbf[(size_t)row * 256 + clo]);
    shi -= d * bf2f(xbf[(size_t)row * 256 + chi]);
  } else {
    slo = fmaxf(slo + bias[clo], 0.f);
    shi = fmaxf(shi + bias[chi], 0.f);
  }
  Cb[(size_t)row * 256 + clo] = f2bf(slo);
  Cb[(size_t)row * 256 + chi] = f2bf(shi);
}

// fused: base=relu(sum(adj_f partials)+bp); lp=(g+1)*base+beta; L2-normalize;
// xin_bf = bf16(0.5*(x+lp/nrm)). One row per block, 128 threads.
__global__ __launch_bounds__(128)
void fuse_red_k(const unsigned* __restrict__ part, const float* __restrict__ bp,
                const u16* __restrict__ gbuf, const u16* __restrict__ xbf,
                u16* __restrict__ xin_bf) {
  const int row = blockIdx.x, uc = threadIdx.x;
  const size_t S = (size_t)8192 * 128;
  const size_t b = (size_t)row * 128 + uc;
  float slo = 0.f, shi = 0.f;
#pragma unroll
  for (int p = 0; p < 4; ++p) {
    unsigned v = part[b + (size_t)p * S];
    slo += bf2f((u16)(v & 0xffff));
    shi += bf2f((u16)(v >> 16));
  }
  const int clo = (uc & 15) + ((uc >> 4) << 5), chi = clo + 16;
  float baselo = fmaxf(slo + bp[clo], 0.f);
  float basehi = fmaxf(shi + bp[chi], 0.f);
  float glo = bf2f(gbuf[(size_t)row * 512 + clo]);
  float ghi = bf2f(gbuf[(size_t)row * 512 + chi]);
  float btlo = bf2f(gbuf[(size_t)row * 512 + 256 + clo]);
  float bthi = bf2f(gbuf[(size_t)row * 512 + 256 + chi]);
  float lplo = (glo + 1.f) * baselo + btlo;
  float lphi = (ghi + 1.f) * basehi + bthi;
  float ss = lplo * lplo + lphi * lphi;
#pragma unroll
  for (int off = 32; off >= 1; off >>= 1) ss += __shfl_xor(ss, off);
  __shared__ float wsum[2];
  if ((uc & 63) == 0) wsum[uc >> 6] = ss;
  __syncthreads();
  float inv = 1.f / fmaxf(sqrtf(wsum[0] + wsum[1]), 1e-12f);
  xin_bf[(size_t)row * 256 + clo] =
      f2bf(0.5f * (bf2f(xbf[(size_t)row * 256 + clo]) + lplo * inv));
  xin_bf[(size_t)row * 256 + chi] =
      f2bf(0.5f * (bf2f(xbf[(size_t)row * 256 + chi]) + lphi * inv));
}

// reduce logits partials [4][8192][64] f32 + b2, then log_softmax over 40 cols
__global__ __launch_bounds__(256)
void reduce_lsm_k(const float* __restrict__ part, const float* __restrict__ b2,
                  float* __restrict__ out) {
  const int t = threadIdx.x, lane = t & 63, w = t >> 6;
  const int row = blockIdx.x * 4 + w;
  const size_t i = (size_t)row * 64 + lane;
  const size_t S = (size_t)8192 * 64;
  float v = 0.f;
#pragma unroll
  for (int p = 0; p < 4; ++p) v += part[i + (size_t)p * S];
  v = (lane < 40) ? v + b2[lane] : -1e30f;
  float mx = v;
#pragma unroll
  for (int off = 32; off >= 1; off >>= 1) mx = fmaxf(mx, __shfl_xor(mx, off));
  float e = (lane < 40) ? expf(v - mx) : 0.f;
#pragma unroll
  for (int off = 32; off >= 1; off >>= 1) e += __shfl_xor(e, off);
  float ls = mx + logf(e);
  if (lane < 40) out[(size_t)row * 40 + lane] = v - ls;
}

extern "C" void kernel_launch(void* const* d_in, const int* in_sizes, int n_in,
                              void* d_out, int out_size, void* d_ws, size_t ws_size,
                              hipStream_t stream) {
  const float* x = (const float*)d_in[0];
  const float* adj_f = (const float*)d_in[1];
  const float* adj_a = (const float*)d_in[2];
  const float* Wp = (const float*)d_in[3];
  const float* bp = (const float*)d_in[4];
  const float* Wg = (const float*)d_in[5];
  const float* Wb = (const float*)d_in[6];
  const float* W1 = (const float*)d_in[7];
  const float* b1 = (const float*)d_in[8];
  const float* W2 = (const float*)d_in[9];
  const float* b2 = (const float*)d_in[10];
  float* out = (float*)d_out;

  char* ws = (char*)d_ws;
  size_t off = 0;
  auto alloc = [&](size_t bytes) {
    char* p = ws + off;
    off += (bytes + 255) & ~(size_t)255;
    return p;
  };
  unsigned* partA = (unsigned*)alloc((size_t)4 * 8192 * 128 * 4);  // 16 MB (adj_f)
  unsigned* partB = (unsigned*)alloc((size_t)4 * 8192 * 128 * 4);  // 16 MB (neigh/h/logits)
  float* partBF = (float*)partB;
  u16* featT = (u16*)alloc((size_t)256 * 8192 * 2);
  u16* featT64 = (u16*)alloc((size_t)64 * 8192 * 2);
  u16* xT = (u16*)alloc((size_t)256 * 8192 * 2);
  u16* xbf = (u16*)alloc((size_t)8192 * 256 * 2);
  u16* xin_bf = (u16*)alloc((size_t)8192 * 256 * 2);
  u16* neigh_bf = (u16*)alloc((size_t)8192 * 256 * 2);
  u16* h_bf = (u16*)alloc((size_t)8192 * 256 * 2);
  u16* gbuf = (u16*)alloc((size_t)8192 * 512 * 2);
  u16* WpT = (u16*)alloc(256 * 256 * 2);
  u16* WgbT = (u16*)alloc(512 * 256 * 2);
  u16* W1T = (u16*)alloc(256 * 256 * 2);
  u16* W2T = (u16*)alloc(64 * 256 * 2);
  float* dd = (float*)alloc(8192 * 4);

  const size_t adjBytes = (size_t)8192 * 8192 * 2;
  bool useBf = (ws_size >= off + adjBytes + 256);
  u16* adj_bf = useBf ? (u16*)alloc(adjBytes) : nullptr;

  dim3 b256(256), b512(512);
  prep_w_k<<<dim3(8, 8, 5), b256, 0, stream>>>(Wp, Wg, Wb, W1, W2, WpT, WgbT, W1T, W2T);
  prep_x_k<<<dim3(8, 256), b256, 0, stream>>>(x, adj_a, xT, xbf, dd);

  // t1^T = (x @ Wp)^T
  sgemm_k<128, 0, 1><<<dim3(256, 2), b256, 0, stream>>>(xbf, WpT, nullptr, 0, featT);
  // merged: adj_f partials (blocks 0-511) + neigh partials/adj_bf (512-1023)
  if (useBf)
    bgemm2_k<true><<<1024, b512, 0, stream>>>(adj_f, featT, partA, adj_a, xT, partB, adj_bf);
  else
    bgemm2_k<false><<<1024, b512, 0, stream>>>(adj_f, featT, partA, adj_a, xT, partB, nullptr);
  reduce4p_k<1><<<4096, b256, 0, stream>>>(partB, nullptr, dd, xbf, neigh_bf);
  // gamma|beta = leaky(neigh @ [Wg|Wb]) -> gbuf bf16 [8192][512]
  sgemm_k<128, 2, 2><<<dim3(256, 4), b256, 0, stream>>>(neigh_bf, WgbT, nullptr, 512, gbuf);
  // fused: base-reduce(adj_f partials) + prompt-mix + normalize -> xin_bf
  fuse_red_k<<<8192, dim3(128), 0, stream>>>(partA, bp, gbuf, xbf, xin_bf);
  // t2^T = (x_in @ W1)^T
  sgemm_k<128, 0, 1><<<dim3(256, 2), b256, 0, stream>>>(xin_bf, W1T, nullptr, 0, featT);
  // h = relu(adj_a @ t2 + b1)  (adj_bf L3-hot)
  if (useBf)
    bgemm_k<256, true, false, true><<<512, b512, 0, stream>>>(adj_bf, featT, partB, nullptr);
  else
    bgemm_k<256, false, false, true><<<512, b512, 0, stream>>>(adj_a, featT, partB, nullptr);
  reduce4p_k<2><<<4096, b256, 0, stream>>>(partB, b1, nullptr, nullptr, h_bf);
  // t3^T = (h @ W2)^T
  sgemm_k<64, 0, 1><<<dim3(256, 1), b256, 0, stream>>>(h_bf, W2T, nullptr, 0, featT64);
  // logits partials (f32) then fused reduce + log_softmax
  if (useBf)
    bgemm_k<64, true, false, false><<<512, b512, 0, stream>>>(adj_bf, featT64, partB, nullptr);
  else
    bgemm_k<64, false, false, false><<<512, b512, 0, stream>>>(adj_a, featT64, partB, nullptr);
  reduce_lsm_k<<<2048, b256, 0, stream>>>(partBF, b2, out);
}